// Round 2
// baseline (1002.497 us; speedup 1.0000x reference)
//
#include <hip/hip_runtime.h>
#include <hip/hip_bf16.h>

typedef __attribute__((ext_vector_type(8))) short bfrag8;   // 8 bf16 in 4 VGPRs
typedef __attribute__((ext_vector_type(4))) float f32x4;

#define DIV_UP(a,b) (((a)+(b)-1)/(b))

__device__ __forceinline__ float sigm(float x){ return 1.0f/(1.0f + __expf(-x)); }
__device__ __forceinline__ float fast_tanh(float x){
  float ax = fabsf(x);
  float t = __expf(-2.0f*ax);
  float r = (1.0f - t)/(1.0f + t);
  return copysignf(r, x);
}

__device__ __forceinline__ float cload(const float* c, size_t i){ return c[i]; }
__device__ __forceinline__ float cload(const __hip_bfloat16* c, size_t i){ return __bfloat162float(c[i]); }
__device__ __forceinline__ void  cstore(float* c, size_t i, float v){ c[i] = v; }
__device__ __forceinline__ void  cstore(__hip_bfloat16* c, size_t i, float v){ c[i] = __float2bfloat16(v); }

#define GLOAD_LDS16(g, l) \
  __builtin_amdgcn_global_load_lds((const __attribute__((address_space(1))) void*)(g), \
                                   (__attribute__((address_space(3))) void*)(l), 16, 0, 0)

// ---------------- weight / embedding conversion (fp32 -> bf16, transposed/padded) --------
__global__ void conv_emb(const float* __restrict__ e, __hip_bfloat16* __restrict__ o){
  int idx = blockIdx.x*256 + threadIdx.x;           // [32000][320] padded
  if (idx >= 32000*320) return;
  int v = idx / 320, k = idx - v*320;
  o[idx] = __float2bfloat16(k < 300 ? e[v*300 + k] : 0.0f);
}
__global__ void conv_wiou(const float* __restrict__ Wf, __hip_bfloat16* __restrict__ o){
  int idx = blockIdx.x*256 + threadIdx.x;           // [768][320]  WiouT[n][k]
  if (idx >= 768*320) return;
  int n = idx / 320, k = idx - n*320;
  o[idx] = __float2bfloat16(k < 300 ? Wf[k*768 + n] : 0.0f);
}
__global__ void conv_ucat(const float* __restrict__ Ui, const float* __restrict__ Uf,
                          __hip_bfloat16* __restrict__ o){
  int idx = blockIdx.x*256 + threadIdx.x;           // [1280][512] UcatT[n][k]
  if (idx >= 1280*512) return;
  int n = idx >> 9, k = idx & 511;
  float v = (n < 768) ? Ui[k*768 + n] : Uf[k*512 + (n - 768)];
  o[idx] = __float2bfloat16(v);
}

// ---------------- bf16 GEMM: C[M][N] = A[M][K] * Bt[N][K]^T, m97-style 128x128x32 --------
template<bool GATHER>
__global__ __launch_bounds__(256, 2) void gemm_bf16(
    const short* __restrict__ A,        // levels: h_prev viewed as [M][K] bf16 bits (chunk base)
    const int* __restrict__ wordid,     // leaf gather (chunk base)
    const short* __restrict__ embbf,    // leaf [V][K]
    const short* __restrict__ Bt,       // [N][K]
    __hip_bfloat16* __restrict__ Cout,  // [Mchunk][N]
    int M, int N, int K)                // M = rows in this chunk
{
  __shared__ __align__(16) char lds[16384];
  char* ldsA = lds;             // [128 rows][32 k] bf16, row stride 64B
  char* ldsB = lds + 8192;      // [128 cols][32 k]
  const int t = threadIdx.x;
  const int lane = t & 63;
  const int w = t >> 6;
  const int wr = w >> 1, wc = w & 1;     // 2x2 wave quadrants of 64x64
  const int r0 = wr*64, c0 = wc*64;
  const int frow = lane & 15, g = lane >> 4;
  const int row0 = blockIdx.y * 128, col0 = blockIdx.x * 128;
  const size_t Kb = (size_t)K * 2;

  f32x4 acc[4][4] = {};
  const int nsteps = K >> 5;

  const int cA0 = t, cA1 = t + 256;   // chunk ids (4 chunks of 16B per row)

  for (int ks = 0; ks < nsteps; ++ks) {
    const int kbyte = ks * 64;
    // ---- stage A tile (2 chunks / thread) ----
    {
      int c = cA0, r = c >> 2, q = c & 3;
      int row = row0 + r; row = row < M ? row : M - 1;
      const char* ga = GATHER
        ? (const char*)embbf + (size_t)wordid[row]*Kb + (size_t)(kbyte + q*16)
        : (const char*)A     + (size_t)row*Kb          + (size_t)(kbyte + q*16);
      GLOAD_LDS16(ga, ldsA + c*16);
      c = cA1; r = c >> 2; q = c & 3;
      row = row0 + r; row = row < M ? row : M - 1;
      ga = GATHER
        ? (const char*)embbf + (size_t)wordid[row]*Kb + (size_t)(kbyte + q*16)
        : (const char*)A     + (size_t)row*Kb          + (size_t)(kbyte + q*16);
      GLOAD_LDS16(ga, ldsA + c*16);
    }
    // ---- stage B tile ----
    {
      int c = cA0, r = c >> 2, q = c & 3;
      const char* gb = (const char*)Bt + (size_t)(col0 + r)*Kb + (size_t)(kbyte + q*16);
      GLOAD_LDS16(gb, ldsB + c*16);
      c = cA1; r = c >> 2; q = c & 3;
      gb = (const char*)Bt + (size_t)(col0 + r)*Kb + (size_t)(kbyte + q*16);
      GLOAD_LDS16(gb, ldsB + c*16);
    }
    __syncthreads();   // drains vmcnt (global_load_lds) per compiler semantics

    bfrag8 af[4], bfv[4];
    #pragma unroll
    for (int mi = 0; mi < 4; ++mi)
      af[mi] = *(const bfrag8*)(ldsA + (r0 + mi*16 + frow)*64 + g*16);
    #pragma unroll
    for (int ni = 0; ni < 4; ++ni)
      bfv[ni] = *(const bfrag8*)(ldsB + (c0 + ni*16 + frow)*64 + g*16);
    #pragma unroll
    for (int mi = 0; mi < 4; ++mi)
      #pragma unroll
      for (int ni = 0; ni < 4; ++ni)
        acc[mi][ni] = __builtin_amdgcn_mfma_f32_16x16x32_bf16(af[mi], bfv[ni], acc[mi][ni], 0, 0, 0);
    __syncthreads();
  }

  // ---- store: D row = g*4+reg, col = frow (m89-verified C/D layout) ----
  #pragma unroll
  for (int mi = 0; mi < 4; ++mi) {
    int mbase = row0 + r0 + mi*16 + g*4;
    #pragma unroll
    for (int ni = 0; ni < 4; ++ni) {
      int nn = col0 + c0 + ni*16 + frow;
      #pragma unroll
      for (int r = 0; r < 4; ++r) {
        int m = mbase + r;
        if (m < M) Cout[(size_t)m*N + nn] = __float2bfloat16(acc[mi][ni][r]);
      }
    }
  }
}

// ---------------- gate epilogues (chunk-local scratch, global h/c via p0) ----------------
template<typename CT>
__global__ void gates_leaf(const __hip_bfloat16* __restrict__ s, const float* __restrict__ bW,
                           __hip_bfloat16* __restrict__ h, CT* __restrict__ c, int p0){
  int pl = blockIdx.x, e = threadIdx.x;
  size_t p = (size_t)(p0 + pl);
  const size_t b = (size_t)pl * 768;
  float i = __bfloat162float(s[b + e])       + bW[e];
  float o = __bfloat162float(s[b + 256 + e]) + bW[256 + e];
  float u = __bfloat162float(s[b + 512 + e]) + bW[512 + e];
  float cv = sigm(i) * fast_tanh(u);
  cstore(c, p*256 + e, cv);
  h[p*256 + e] = __float2bfloat16(sigm(o) * fast_tanh(cv));
}

template<typename CT>
__global__ void gates_level(const __hip_bfloat16* __restrict__ s, const float* __restrict__ bUi,
                            const float* __restrict__ bUf, const CT* __restrict__ cprev,
                            __hip_bfloat16* __restrict__ h, CT* __restrict__ c, int p0){
  int pl = blockIdx.x, e = threadIdx.x;
  size_t p = (size_t)(p0 + pl);
  const size_t b = (size_t)pl * 1280;
  float i  = __bfloat162float(s[b + e])        + bUi[e];
  float o  = __bfloat162float(s[b + 256 + e])  + bUi[256 + e];
  float u  = __bfloat162float(s[b + 512 + e])  + bUi[512 + e];
  float f0 = __bfloat162float(s[b + 768 + e])  + bUf[e];
  float f1 = __bfloat162float(s[b + 1024 + e]) + bUf[256 + e];
  float cf = sigm(f0) * cload(cprev, (2*p)*256 + e) + sigm(f1) * cload(cprev, (2*p+1)*256 + e);
  float cv = sigm(i) * fast_tanh(u) + cf;
  cstore(c, p*256 + e, cv);
  h[p*256 + e] = __float2bfloat16(sigm(o) * fast_tanh(cv));
}

// ---------------- output projection: out[row][5] = h[row][0:256] @ W_out + b ------------
__global__ void outproj(const __hip_bfloat16* __restrict__ h, int M,
                        const float* __restrict__ Wout, const float* __restrict__ bout,
                        float* __restrict__ out){
  int w = threadIdx.x >> 6, lane = threadIdx.x & 63;
  int row = blockIdx.x*4 + w;
  if (row >= M) return;
  float a0=0,a1=0,a2=0,a3=0,a4=0;
  #pragma unroll
  for (int j = 0; j < 4; ++j){
    int e = j*64 + lane;
    float hv = __bfloat162float(h[(size_t)row*256 + e]);
    const float* wp = Wout + e*5;
    a0 += hv*wp[0]; a1 += hv*wp[1]; a2 += hv*wp[2]; a3 += hv*wp[3]; a4 += hv*wp[4];
  }
  #pragma unroll
  for (int off = 32; off; off >>= 1){
    a0 += __shfl_down(a0, off); a1 += __shfl_down(a1, off); a2 += __shfl_down(a2, off);
    a3 += __shfl_down(a3, off); a4 += __shfl_down(a4, off);
  }
  if (lane == 0){
    float* op = out + (size_t)row*5;
    op[0]=a0+bout[0]; op[1]=a1+bout[1]; op[2]=a2+bout[2]; op[3]=a3+bout[3]; op[4]=a4+bout[4];
  }
}

extern "C" void kernel_launch(void* const* d_in, const int* in_sizes, int n_in,
                              void* d_out, int out_size, void* d_ws, size_t ws_size,
                              hipStream_t stream) {
  const int V = 32000, Kp = 320;
  const size_t R0 = 131072, R1 = 65536;   // leaf rows, level-1 rows
  const int* wordid   = (const int*)d_in[0];
  const float* emb    = (const float*)d_in[1];
  const float* W_iou  = (const float*)d_in[2];
  const float* b_Wiou = (const float*)d_in[3];
  const float* U_iou  = (const float*)d_in[4];
  const float* b_Uiou = (const float*)d_in[5];
  const float* U_f    = (const float*)d_in[6];
  const float* b_Uf   = (const float*)d_in[7];
  const float* W_out  = (const float*)d_in[8];
  const float* b_out  = (const float*)d_in[9];
  float* out = (float*)d_out;

  auto al = [](size_t x){ return (x + 255) & ~(size_t)255; };
  const size_t sz_emb  = al((size_t)V*Kp*2);
  const size_t sz_wiou = al((size_t)768*Kp*2);
  const size_t sz_ucat = al((size_t)1280*512*2);
  const size_t sz_h    = al(R0*256*2) + al(R1*256*2);
  const size_t fixed   = sz_emb + sz_wiou + sz_ucat + sz_h;

  // ---- adaptive plan: pick largest (c precision, chunk) that fits ws_size ----
  struct Plan { bool c32; int chunk; };
  const Plan plans[4] = { {true,32768}, {true,8192}, {false,8192}, {false,2048} };
  Plan pl = plans[3];
  for (int i = 0; i < 4; ++i) {
    size_t csz = plans[i].c32 ? (al(R0*256*4) + al(R1*256*4)) : (al(R0*256*2) + al(R1*256*2));
    size_t ssz = al((size_t)plans[i].chunk * 1280 * 2);
    if (fixed + csz + ssz <= ws_size) { pl = plans[i]; break; }
  }
  const int CH = pl.chunk;
  const size_t cElt = pl.c32 ? 4 : 2;

  char* p = (char*)d_ws;
  auto take = [&](size_t bytes){ char* r = p; p += (bytes + 255) & ~(size_t)255; return r; };
  __hip_bfloat16* embbf = (__hip_bfloat16*)take((size_t)V*Kp*2);
  __hip_bfloat16* wiouT = (__hip_bfloat16*)take((size_t)768*Kp*2);
  __hip_bfloat16* ucatT = (__hip_bfloat16*)take((size_t)1280*512*2);
  __hip_bfloat16* hA    = (__hip_bfloat16*)take(R0*256*2);
  __hip_bfloat16* hB    = (__hip_bfloat16*)take(R1*256*2);
  void*           cA    = (void*)take(R0*256*cElt);
  void*           cB    = (void*)take(R1*256*cElt);
  __hip_bfloat16* scr   = (__hip_bfloat16*)take((size_t)CH*1280*2);

  conv_emb <<<DIV_UP(V*Kp,    256), 256, 0, stream>>>(emb, embbf);
  conv_wiou<<<DIV_UP(768*Kp,  256), 256, 0, stream>>>(W_iou, wiouT);
  conv_ucat<<<DIV_UP(1280*512,256), 256, 0, stream>>>(U_iou, U_f, ucatT);

  // ---- leaves (level 0), chunked ----
  for (size_t rb = 0; rb < R0; rb += CH) {
    int rows = (int)((R0 - rb) < (size_t)CH ? (R0 - rb) : (size_t)CH);
    gemm_bf16<true><<<dim3(768/128, DIV_UP(rows,128)), 256, 0, stream>>>(
        nullptr, wordid + rb, (const short*)embbf, (const short*)wiouT, scr, rows, 768, Kp);
    if (pl.c32)
      gates_leaf<float><<<rows, 256, 0, stream>>>(scr, b_Wiou, hA, (float*)cA, (int)rb);
    else
      gates_leaf<__hip_bfloat16><<<rows, 256, 0, stream>>>(scr, b_Wiou, hA, (__hip_bfloat16*)cA, (int)rb);
  }
  outproj<<<DIV_UP(R0,4), 256, 0, stream>>>(hA, (int)R0, W_out, b_out, out);

  // ---- tree levels 1..11 ----
  size_t rowoff = R0;
  const __hip_bfloat16* hp = hA; const void* cp = cA;
  int n = 2048;
  for (int lvl = 1; lvl <= 11; ++lvl) {
    n >>= 1; int M = 64 * n;
    __hip_bfloat16* hn = (lvl & 1) ? hB : hA;
    void*           cn = (lvl & 1) ? cB : cA;
    for (int rb = 0; rb < M; rb += CH) {
      int rows = (M - rb) < CH ? (M - rb) : CH;
      gemm_bf16<false><<<dim3(1280/128, DIV_UP(rows,128)), 256, 0, stream>>>(
          (const short*)hp + (size_t)rb*512, nullptr, nullptr, (const short*)ucatT,
          scr, rows, 1280, 512);
      if (pl.c32)
        gates_level<float><<<rows, 256, 0, stream>>>(scr, b_Uiou, b_Uf,
            (const float*)cp, hn, (float*)cn, rb);
      else
        gates_level<__hip_bfloat16><<<rows, 256, 0, stream>>>(scr, b_Uiou, b_Uf,
            (const __hip_bfloat16*)cp, hn, (__hip_bfloat16*)cn, rb);
    }
    outproj<<<DIV_UP(M,4), 256, 0, stream>>>(hn, M, W_out, b_out, out + rowoff*5);
    hp = hn; cp = cn; rowoff += M;
  }
}

// Round 3
// 565.963 us; speedup vs baseline: 1.7713x; 1.7713x over previous
//
#include <hip/hip_runtime.h>
#include <hip/hip_bf16.h>

typedef __attribute__((ext_vector_type(8))) short bfrag8;   // 8 bf16 in 4 VGPRs
typedef __attribute__((ext_vector_type(4))) float f32x4;

#define DIV_UP(a,b) (((a)+(b)-1)/(b))

__device__ __forceinline__ float sigm(float x){ return 1.0f/(1.0f + __expf(-x)); }
__device__ __forceinline__ float fast_tanh(float x){
  float ax = fabsf(x);
  float t = __expf(-2.0f*ax);
  float r = (1.0f - t)/(1.0f + t);
  return copysignf(r, x);
}
__device__ __forceinline__ float bf2f(short s){
  unsigned int u = ((unsigned int)(unsigned short)s) << 16;
  return __uint_as_float(u);
}

#define GLOAD_LDS16(g, l) \
  __builtin_amdgcn_global_load_lds((const __attribute__((address_space(1))) void*)(g), \
                                   (__attribute__((address_space(3))) void*)(l), 16, 0, 0)

// ---------------- weight / embedding conversion ----------------
__global__ void conv_emb(const float* __restrict__ e, __hip_bfloat16* __restrict__ o){
  int idx = blockIdx.x*256 + threadIdx.x;           // [32000][320] padded
  if (idx >= 32000*320) return;
  int v = idx / 320, k = idx - v*320;
  o[idx] = __float2bfloat16(k < 300 ? e[v*300 + k] : 0.0f);
}
// WiouT interleaved: n = (e>>4)*48 + gate*16 + (e&15), gate in {i,o,u}; [768][320]
__global__ void conv_wiou_i(const float* __restrict__ Wf, __hip_bfloat16* __restrict__ o){
  int idx = blockIdx.x*256 + threadIdx.x;
  if (idx >= 768*320) return;
  int n = idx / 320, k = idx - n*320;
  int eg = n / 48, rem = n - eg*48, gate = rem >> 4, es = rem & 15;
  int e = eg*16 + es;
  o[idx] = __float2bfloat16(k < 300 ? Wf[(size_t)k*768 + gate*256 + e] : 0.0f);
}
// UcatT interleaved: n = (e>>4)*80 + gate*16 + (e&15), gate in {i,o,u,f0,f1}; [1280][512]
__global__ void conv_ucat_i(const float* __restrict__ Ui, const float* __restrict__ Uf,
                            __hip_bfloat16* __restrict__ o){
  int idx = blockIdx.x*256 + threadIdx.x;
  if (idx >= 1280*512) return;
  int n = idx >> 9, k = idx & 511;
  int eg = n / 80, rem = n - eg*80, gate = rem >> 4, es = rem & 15;
  int e = eg*16 + es;
  float v = (gate < 3) ? Ui[(size_t)k*768 + gate*256 + e]
                       : Uf[(size_t)k*512 + (gate-3)*256 + e];
  o[idx] = __float2bfloat16(v);
}

// ---------------- fused GEMM + gates ----------------
// C[m][n] = A[m][:] . Bt[n][:] with Bt column-interleaved by gate; epilogue applies
// TreeLSTM gates entirely lane-locally (all NG gates of element e live in lane frow=e&15).
// LDS XOR-swizzle: logical (row, byte b) -> phys rp*128 + ((( (row&1)*4 + (b>>4) )^(rp&7))*16) + (b&15),
// rp=row>>1. Staged linearly (global_load_lds) via de-swizzled source order; read with swizzled offsets.
template<int NG, bool G2>
__global__ __launch_bounds__(256, 2) void gemm_fused(
    const char* __restrict__ Ab,      // A bytes (direct) | h_voc bytes (G2: gather pairs)
    const int*  __restrict__ wid,     // G2 only: leaf wordids (children 2m, 2m+1)
    const char* __restrict__ Btb,     // interleaved [N][K] bf16
    int M, int K, int Kb,             // Kb = A row bytes (direct mode)
    const float* __restrict__ b_iou,  // [768] original layout
    const float* __restrict__ b_f,    // [512] (NG=5)
    const float* __restrict__ cprev,  // fp32 children c (table when G2)
    __hip_bfloat16* __restrict__ Hout, float* __restrict__ Cout)
{
  constexpr int GW  = NG*16;          // wave col width (one e-group, NG gates)
  constexpr int BN  = 2*GW;           // block cols
  constexpr int BCH = BN*4;           // B chunks (16B) per K-step
  __shared__ __align__(16) char lds[8192 + BN*64];
  char* ldsA = lds; char* ldsB = lds + 8192;
  const int t = threadIdx.x, lane = t & 63, w = t >> 6;
  const int wr = w >> 1, wc = w & 1;
  const int frow = lane & 15, g = lane >> 4;
  const int row0 = blockIdx.y*128;
  const size_t colbase = (size_t)blockIdx.x * BN;
  const size_t Kbyt = (size_t)K*2;

  // ---- ks-invariant staging descriptors (de-swizzled chunk -> (row,q)) ----
  const char* abase0[2]; const char* abase1[2];
  #pragma unroll
  for (int i = 0; i < 2; ++i) {
    int c = t + i*256;
    int rp = c >> 3, lc = (c & 7) ^ (rp & 7);
    int r = rp*2 + (lc >> 2), q = lc & 3;
    int row = row0 + r; row = row < M ? row : M-1;
    if constexpr (G2) {
      abase0[i] = Ab + (size_t)wid[2*row]  *512 + q*16;
      abase1[i] = Ab + (size_t)wid[2*row+1]*512 + q*16 - 512;
    } else {
      abase0[i] = Ab + (size_t)row*Kb + q*16;
      abase1[i] = abase0[i];
    }
  }
  const char* bbase[3];
  const int nb = (t < 128) ? ((NG==5) ? 3 : 2) : ((NG==5) ? 2 : 1);
  #pragma unroll
  for (int i = 0; i < 3; ++i) {
    int cb = t + i*256;
    if (cb < BCH) {
      int rp = cb >> 3, lc = (cb & 7) ^ (rp & 7);
      int r = rp*2 + (lc >> 2), q = lc & 3;
      bbase[i] = Btb + (colbase + r)*Kbyt + q*16;
    } else bbase[i] = Btb;
  }

  // swizzled read offsets (lane-constant across mi/gi)
  const int fr2 = frow >> 1;
  const int pc  = (((frow & 1)*4 + g) ^ (fr2 & 7));
  const int aoff = wr*4096 + fr2*128 + pc*16;
  const int boff = wc*(GW*64) + fr2*128 + pc*16;

  f32x4 acc[4][NG] = {};
  const int nsteps = K >> 5;
  for (int ks = 0; ks < nsteps; ++ks) {
    const int kb0 = ks*64;
    #pragma unroll
    for (int i = 0; i < 2; ++i) {
      const char* s = (G2 && kb0 >= 512) ? abase1[i] + kb0 : abase0[i] + kb0;
      GLOAD_LDS16(s, ldsA + (t + i*256)*16);
    }
    #pragma unroll
    for (int i = 0; i < 3; ++i)
      if (i < nb) GLOAD_LDS16(bbase[i] + kb0, ldsB + (t + i*256)*16);
    __syncthreads();

    bfrag8 af[4], bfv[NG];
    #pragma unroll
    for (int mi = 0; mi < 4; ++mi) af[mi] = *(const bfrag8*)(ldsA + aoff + mi*1024);
    #pragma unroll
    for (int gi = 0; gi < NG; ++gi) bfv[gi] = *(const bfrag8*)(ldsB + boff + gi*1024);
    #pragma unroll
    for (int mi = 0; mi < 4; ++mi)
      #pragma unroll
      for (int gi = 0; gi < NG; ++gi)
        acc[mi][gi] = __builtin_amdgcn_mfma_f32_16x16x32_bf16(af[mi], bfv[gi], acc[mi][gi], 0, 0, 0);
    __syncthreads();
  }

  // ---- fused gate epilogue (C/D layout: col=frow, row=g*4+r) ----
  const int e = blockIdx.x*32 + wc*16 + frow;
  const float bi = b_iou[e], bo = b_iou[256+e], bu = b_iou[512+e];
  float bf0 = 0.f, bf1 = 0.f;
  if constexpr (NG == 5) { bf0 = b_f[e]; bf1 = b_f[256+e]; }
  #pragma unroll
  for (int mi = 0; mi < 4; ++mi) {
    const int mb = row0 + wr*64 + mi*16 + g*4;
    #pragma unroll
    for (int r = 0; r < 4; ++r) {
      const int m = mb + r;
      if (m < M) {
        float cv = sigm(acc[mi][0][r] + bi) * fast_tanh(acc[mi][2][r] + bu);
        if constexpr (NG == 5) {
          const size_t c0i = G2 ? (size_t)wid[2*m]   : (size_t)(2*m);
          const size_t c1i = G2 ? (size_t)wid[2*m+1] : (size_t)(2*m+1);
          cv += sigm(acc[mi][3][r] + bf0) * cprev[c0i*256 + e]
              + sigm(acc[mi][4][r] + bf1) * cprev[c1i*256 + e];
        }
        Cout[(size_t)m*256 + e] = cv;
        Hout[(size_t)m*256 + e] = __float2bfloat16(sigm(acc[mi][1][r] + bo) * fast_tanh(cv));
      }
    }
  }
}

// ---------------- vectorized output projection ----------------
__global__ void outproj_v(const __hip_bfloat16* __restrict__ h, int M,
                          const float* __restrict__ Wout, const float* __restrict__ bout,
                          float* __restrict__ out){
  const int t = threadIdx.x;
  const int half = t >> 5, l32 = t & 31;
  const int e0 = l32 * 8;
  float wv[8][5];
  #pragma unroll
  for (int j = 0; j < 8; ++j)
    #pragma unroll
    for (int cl = 0; cl < 5; ++cl) wv[j][cl] = Wout[(e0+j)*5 + cl];
  const float b0 = bout[0], b1 = bout[1], b2 = bout[2], b3 = bout[3], b4 = bout[4];
  for (int row = blockIdx.x*8 + half; row < M; row += gridDim.x*8) {
    bfrag8 hv = *(const bfrag8*)((const short*)h + (size_t)row*256 + e0);
    float a0=0,a1=0,a2=0,a3=0,a4=0;
    #pragma unroll
    for (int j = 0; j < 8; ++j) {
      float x = bf2f(hv[j]);
      a0 += x*wv[j][0]; a1 += x*wv[j][1]; a2 += x*wv[j][2]; a3 += x*wv[j][3]; a4 += x*wv[j][4];
    }
    #pragma unroll
    for (int off = 16; off; off >>= 1) {
      a0 += __shfl_down(a0, off); a1 += __shfl_down(a1, off);
      a2 += __shfl_down(a2, off); a3 += __shfl_down(a3, off); a4 += __shfl_down(a4, off);
    }
    if (l32 == 0) {
      float* op = out + (size_t)row*5;
      op[0]=a0+b0; op[1]=a1+b1; op[2]=a2+b2; op[3]=a3+b3; op[4]=a4+b4;
    }
  }
}

// ---------------- leaf output scatter: out[p] = outvoc[wordid[p]] ----------------
__global__ void leaf_scatter(const int* __restrict__ wid, const float* __restrict__ outvoc,
                             float* __restrict__ out){
  int p = blockIdx.x*256 + threadIdx.x;
  if (p >= 131072) return;
  const float* s = outvoc + (size_t)wid[p]*5;
  float* d = out + (size_t)p*5;
  #pragma unroll
  for (int j = 0; j < 5; ++j) d[j] = s[j];
}

extern "C" void kernel_launch(void* const* d_in, const int* in_sizes, int n_in,
                              void* d_out, int out_size, void* d_ws, size_t ws_size,
                              hipStream_t stream) {
  const int* wordid   = (const int*)d_in[0];
  const float* emb    = (const float*)d_in[1];
  const float* W_iou  = (const float*)d_in[2];
  const float* b_Wiou = (const float*)d_in[3];
  const float* U_iou  = (const float*)d_in[4];
  const float* b_Uiou = (const float*)d_in[5];
  const float* U_f    = (const float*)d_in[6];
  const float* b_Uf   = (const float*)d_in[7];
  const float* W_out  = (const float*)d_in[8];
  const float* b_out  = (const float*)d_in[9];
  float* out = (float*)d_out;

  char* p = (char*)d_ws;
  auto take = [&](size_t bytes){ char* r = p; p += (bytes + 255) & ~(size_t)255; return r; };
  __hip_bfloat16* wiouT  = (__hip_bfloat16*)take((size_t)768*320*2);
  __hip_bfloat16* ucatT  = (__hip_bfloat16*)take((size_t)1280*512*2);
  __hip_bfloat16* h_voc  = (__hip_bfloat16*)take((size_t)32000*256*2);   // 16.4 MB
  float*          c_voc  = (float*)take((size_t)32000*256*4);            // 32.8 MB
  float*          outvoc = (float*)take((size_t)32000*5*4);
  __hip_bfloat16* hA     = (__hip_bfloat16*)take((size_t)65536*256*2);   // 33.6 MB
  float*          cA     = (float*)take((size_t)65536*256*4);            // 67.1 MB
  __hip_bfloat16* hB     = (__hip_bfloat16*)take((size_t)32768*256*2);   // 16.8 MB
  float*          cB     = (float*)take((size_t)32768*256*4);            // 33.6 MB
  // embbf aliases cA: dead before first cA write (lvl-1 gates)
  __hip_bfloat16* embbf  = (__hip_bfloat16*)cA;                          // 20.5 MB

  conv_emb   <<<DIV_UP(32000*320,256),256,0,stream>>>(emb, embbf);
  conv_wiou_i<<<DIV_UP(768*320,  256),256,0,stream>>>(W_iou, wiouT);
  conv_ucat_i<<<DIV_UP(1280*512, 256),256,0,stream>>>(U_iou, U_f, ucatT);

  // ---- vocab precompute: h_voc/c_voc = leaf-gates(emb @ W_iou + b); outvoc = h_voc @ W_out + b ----
  gemm_fused<3,false><<<dim3(8,250),256,0,stream>>>(
      (const char*)embbf, nullptr, (const char*)wiouT, 32000, 320, 640,
      b_Wiou, nullptr, nullptr, h_voc, c_voc);
  outproj_v<<<1024,256,0,stream>>>(h_voc, 32000, W_out, b_out, outvoc);
  leaf_scatter<<<DIV_UP(131072,256),256,0,stream>>>(wordid, outvoc, out);

  // ---- level 1: gather children straight from vocab tables ----
  gemm_fused<5,true><<<dim3(8,512),256,0,stream>>>(
      (const char*)h_voc, wordid, (const char*)ucatT, 65536, 512, 0,
      b_Uiou, b_Uf, c_voc, hA, cA);
  outproj_v<<<2048,256,0,stream>>>(hA, 65536, W_out, b_out, out + (size_t)131072*5);

  // ---- levels 2..11 ----
  const __hip_bfloat16* hp = hA; const float* cp = cA;
  size_t rowoff = 131072 + 65536;
  int Mlvl = 65536;
  for (int lvl = 2; lvl <= 11; ++lvl) {
    Mlvl >>= 1;
    __hip_bfloat16* hn = (lvl & 1) ? hA : hB;
    float*          cn = (lvl & 1) ? cA : cB;
    gemm_fused<5,false><<<dim3(8,DIV_UP(Mlvl,128)),256,0,stream>>>(
        (const char*)hp, nullptr, (const char*)ucatT, Mlvl, 512, 1024,
        b_Uiou, b_Uf, cp, hn, cn);
    int opg = DIV_UP(Mlvl,8); if (opg > 2048) opg = 2048;
    outproj_v<<<opg,256,0,stream>>>(hn, Mlvl, W_out, b_out, out + rowoff*5);
    hp = hn; cp = cn; rowoff += Mlvl;
  }
}